// Round 13
// baseline (106.479 us; speedup 1.0000x reference)
//
#include <hip/hip_runtime.h>
#include <hip/hip_bf16.h>
#include <math.h>

// Decoder: h = relu(cat @ W_h + b_h); t = selu(h @ W1 + b1);
// x = sigmoid(t @ W2 + b2); loss = sum_w(softplus(z) - z*img)   [== -(BCE log-lik)]
// R = S*B = 4096 rows; Hn=512, bott=160, P=12288 = 192 groups * 64 (w).

#define SELU_SCALE 1.0507009873554804934193349852946f
#define SELU_ALPHA 1.6732632423543772848170429916717f

typedef __attribute__((ext_vector_type(8))) short bf16x8;   // 8 bf16 (4 VGPRs)
typedef __attribute__((ext_vector_type(4))) float f32x4;    // MFMA accumulator

static __device__ __forceinline__ short f2bf(float x) {
    __hip_bfloat16 h = __float2bfloat16(x);
    short s;
    __builtin_memcpy(&s, &h, 2);
    return s;
}

// ---------------- K0: pack W2 into MFMA-fragment-native order --------------
// w2f chunk = (col16*5 + kk): 64 lanes x 8 bf16 (1 KB contiguous).
__global__ __launch_bounds__(256) void w2_pack_kernel(
    const float* __restrict__ W2,       // [160,12288]
    __hip_bfloat16* __restrict__ w2f)   // [768*5 chunks][512 shorts]
{
    __shared__ float tile[32][64];      // [k within 32][col within 64]
    const int colBase = blockIdx.x * 64;   // 192
    const int kkBase  = blockIdx.y * 32;   // 5
    const int tid = threadIdx.x;

    for (int i = tid; i < 32 * 64; i += 256)
        tile[i >> 6][i & 63] = W2[(size_t)(kkBase + (i >> 6)) * 12288 + colBase + (i & 63)];
    __syncthreads();

    const int c16 = tid >> 6;        // 0..3 (col16 within this block)
    const int lane = tid & 63;
    const int lr = lane & 15, lh = lane >> 4;

    bf16x8 v;
#pragma unroll
    for (int j = 0; j < 8; ++j)
        v[j] = f2bf(tile[lh * 8 + j][c16 * 16 + lr]);

    const size_t chunk = (size_t)(blockIdx.x * 4 + c16) * 5 + blockIdx.y;
    *(bf16x8*)((short*)w2f + chunk * 512 + lane * 8) = v;
}

// ---------------- K1: h[R,512] = bf16(relu(cat @ Wh + bh)) -----------------
__global__ __launch_bounds__(512) void dec_hidden_kernel(
    const float* __restrict__ digits,   // [R,10]
    const float* __restrict__ styles,   // [R,50]
    const float* __restrict__ Wh,       // [60,512]
    const float* __restrict__ bh,       // [512]
    __hip_bfloat16* __restrict__ h)     // [R,512] bf16
{
    __shared__ float cat_s[8][60];
    const int tid = threadIdx.x;
    const int rowBase = blockIdx.x * 8;

    for (int i = tid; i < 8 * 60; i += 512) {
        const int r = i / 60, k = i % 60;
        const int row = rowBase + r;
        cat_s[r][k] = (k < 10) ? digits[row * 10 + k]
                               : styles[row * 50 + (k - 10)];
    }
    __syncthreads();

    float acc[8];
    const float bias = bh[tid];
#pragma unroll
    for (int r = 0; r < 8; ++r) acc[r] = bias;

    for (int k = 0; k < 60; ++k) {
        const float w = Wh[k * 512 + tid];
#pragma unroll
        for (int r = 0; r < 8; ++r) acc[r] = fmaf(cat_s[r][k], w, acc[r]);
    }
#pragma unroll
    for (int r = 0; r < 8; ++r)
        h[(size_t)(rowBase + r) * 512 + tid] = __float2bfloat16(fmaxf(acc[r], 0.0f));
}

// ---------------- K2: t[R,160] = bf16(selu(h @ W1 + b1)) -------------------
__global__ __launch_bounds__(192) void hidden1_kernel(
    const __hip_bfloat16* __restrict__ h,   // [R,512] bf16
    const float* __restrict__ W1,           // [512,160]
    const float* __restrict__ b1,           // [160]
    __hip_bfloat16* __restrict__ t)         // [R,160] bf16
{
    __shared__ float h_s[8 * 512];
    const int tid = threadIdx.x;
    const int rowBase = blockIdx.x * 8;
    const __hip_bfloat16* hsrc = h + (size_t)rowBase * 512;
    for (int i = tid; i < 8 * 512; i += 192) h_s[i] = __bfloat162float(hsrc[i]);
    __syncthreads();

    if (tid < 160) {
        float acc[8];
        const float bias = b1[tid];
#pragma unroll
        for (int r = 0; r < 8; ++r) acc[r] = bias;

        for (int k = 0; k < 512; k += 4) {
            const float w0 = W1[(size_t)(k + 0) * 160 + tid];
            const float w1 = W1[(size_t)(k + 1) * 160 + tid];
            const float w2 = W1[(size_t)(k + 2) * 160 + tid];
            const float w3 = W1[(size_t)(k + 3) * 160 + tid];
#pragma unroll
            for (int r = 0; r < 8; ++r) {
                const float4 hv = *(const float4*)&h_s[r * 512 + k];
                float a = acc[r];
                a = fmaf(hv.x, w0, a);
                a = fmaf(hv.y, w1, a);
                a = fmaf(hv.z, w2, a);
                a = fmaf(hv.w, w3, a);
                acc[r] = a;
            }
        }
#pragma unroll
        for (int r = 0; r < 8; ++r) {
            const float z = acc[r];
            const float s = (z > 0.0f) ? (SELU_SCALE * z)
                                       : (SELU_SCALE * SELU_ALPHA * expm1f(z));
            t[(size_t)(rowBase + r) * 160 + tid] = __float2bfloat16(s);
        }
    }
}

// ---------------- K2b: pack t into fragment-native chunks ------------------
__global__ __launch_bounds__(256) void t_pack_kernel(
    const __hip_bfloat16* __restrict__ t,   // [4096,160]
    __hip_bfloat16* __restrict__ tf)        // [1280 chunks][512 shorts]
{
    const int lane = threadIdx.x & 63;
    const int cidx = blockIdx.x * 4 + (threadIdx.x >> 6);  // 0..1279
    const int r16 = cidx / 5, kk = cidx % 5;
    const short* tb = (const short*)t;
    const bf16x8 v = *(const bf16x8*)(tb
        + (size_t)(r16 * 16 + (lane & 15)) * 160 + kk * 32 + (lane >> 4) * 8);
    *(bf16x8*)((short*)tf + (size_t)cidx * 512 + lane * 8) = v;
}

// ---------------- K3: pipelined MFMA GEMM + fused sigmoid-BCE loss ---------
// grid (192 colgroups, 8); block 256 = 4 waves, wave = private 32-row x
// 64-col quadrant (R6/R10 geometry). Each block runs FOUR row-tiles
// (rows (blockIdx.y*4+it)*128). Per-wave software pipeline: tile it+1's
// image DMAs are issued right after tile it's ims->reg readback, so the
// memory system sees a sustained request stream (fix for the burst-gap
// pattern that capped R10/R12 at ~3.3 TB/s). w2f chunks are L2-hot and
// reused across the 4 tiles (refetch / 4). No __syncthreads (wave-private
// LDS); explicit vmcnt/lgkm fences order read-before-overwrite.
__global__ __launch_bounds__(256, 4) void out_loss_mfma_kernel(
    const __hip_bfloat16* __restrict__ tf,   // fragment-packed t
    const __hip_bfloat16* __restrict__ w2f,  // fragment-packed W2
    const float* __restrict__ b2,            // [12288]
    const float* __restrict__ images,        // [4096,12288]
    float* __restrict__ out)                 // [4096,192]
{
    __shared__ float ims[4][2048];           // 32 KB: per-wave 32x64 images

    const int tid = threadIdx.x;
    const int lane = tid & 63;
    const int wv = tid >> 6;
    const int colBlk = blockIdx.x;                 // 0..191
    const int colBase = colBlk * 64;
    const int lr = lane & 15;
    const int lh = lane >> 4;

    const short* wfb = (const short*)w2f;
    const short* tfb = (const short*)tf;
    const char* imb = (const char*)images;
    const int c16base = colBlk * 4;

    // DMA helper indices (per-wave private quadrant, R6-verified swizzle)
    const int rsub = lane >> 4;          // row within instruction (0..3)
    const int m16 = lane & 15;           // 16B chunk within 256B row

    // ---- prologue: DMA tile 0's quadrant ----
    {
        const int rowB = (blockIdx.y * 4 + 0) * 128 + wv * 32;
#pragma unroll
        for (int w = 0; w < 8; ++w) {
            const int r = w * 4 + rsub;
            const size_t gb = (size_t)(rowB + r) * 49152 + (size_t)colBase * 4
                            + (size_t)((16 * m16) ^ ((r & 15) << 4));
            __builtin_amdgcn_global_load_lds((const uint32_t*)(imb + gb),
                (uint32_t*)&ims[wv][w * 256], 16, 0, 0);
        }
    }

    // bias quads: col-invariant across tiles -> hoisted (16 VGPR)
    float4 bc[4];
#pragma unroll
    for (int c = 0; c < 4; ++c)
        bc[c] = *(const float4*)(b2 + colBase + c * 16 + lh * 4);

#pragma unroll
    for (int it = 0; it < 4; ++it) {
        const int rowBase = (blockIdx.y * 4 + it) * 128 + wv * 32;
        const int r16base = rowBase >> 4;

        // ---- GEMM tile it (frag loads force-drain tile-it DMAs: they were
        // issued a full iteration ago, so the drain is free) ----
        f32x4 acc[4][2] = {};   // [cw][rw]
#pragma unroll
        for (int kk = 0; kk < 5; ++kk) {
            bf16x8 bT[2], aW[4];
#pragma unroll
            for (int r = 0; r < 2; ++r)
                bT[r] = *(const bf16x8*)(tfb
                    + ((size_t)(r16base + r) * 5 + kk) * 512 + lane * 8);
#pragma unroll
            for (int c = 0; c < 4; ++c)
                aW[c] = *(const bf16x8*)(wfb
                    + ((size_t)(c16base + c) * 5 + kk) * 512 + lane * 8);
#pragma unroll
            for (int c = 0; c < 4; ++c)
#pragma unroll
                for (int r = 0; r < 2; ++r)
                    acc[c][r] = __builtin_amdgcn_mfma_f32_16x16x32_bf16(
                        aW[c], bT[r], acc[c][r], 0, 0, 0);
        }

        // ---- ims -> regs (tile it), then release the slab ----
        asm volatile("s_waitcnt vmcnt(0)" ::: "memory");   // DMAs landed
        __builtin_amdgcn_sched_barrier(0);
        float4 img[2][4];
#pragma unroll
        for (int rw = 0; rw < 2; ++rw)
#pragma unroll
            for (int c = 0; c < 4; ++c) {
                const int fidx = (rw * 16 + lr) * 64 + ((lh * 4 + c * 16) ^ (lr << 2));
                img[rw][c] = *(const float4*)&ims[wv][fidx];   // ds_read_b128
            }
        asm volatile("s_waitcnt lgkmcnt(0)" ::: "memory");  // reads done
        __builtin_amdgcn_sched_barrier(0);

        // ---- issue tile it+1's DMAs (land during epilogue + next GEMM) ----
        if (it < 3) {
            const int rowN = (blockIdx.y * 4 + it + 1) * 128 + wv * 32;
#pragma unroll
            for (int w = 0; w < 8; ++w) {
                const int r = w * 4 + rsub;
                const size_t gb = (size_t)(rowN + r) * 49152 + (size_t)colBase * 4
                                + (size_t)((16 * m16) ^ ((r & 15) << 4));
                __builtin_amdgcn_global_load_lds((const uint32_t*)(imb + gb),
                    (uint32_t*)&ims[wv][w * 256], 16, 0, 0);
            }
        }
        __builtin_amdgcn_sched_barrier(0);

        // ---- epilogue: softplus(z) - z*img, reduce over 64 cols ----
#pragma unroll
        for (int rw = 0; rw < 2; ++rw) {
            float mx = 0.f;   // Σ max(z,0)
            float pr = 1.f;   // Π (1+e^{-|z|})  (16 terms, fp32-safe)
            float zi = 0.f;   // Σ z*im
#pragma unroll
            for (int c = 0; c < 4; ++c) {
                const float imv[4] = {img[rw][c].x, img[rw][c].y,
                                      img[rw][c].z, img[rw][c].w};
                const float bcv[4] = {bc[c].x, bc[c].y, bc[c].z, bc[c].w};
#pragma unroll
                for (int j = 0; j < 4; ++j) {
                    const float z = acc[c][rw][j] + bcv[j];
                    mx += fmaxf(z, 0.0f);
                    pr *= 1.0f + __expf(-fabsf(z));   // native v_exp_f32
                    zi = fmaf(z, imv[j], zi);
                }
            }
            float part = mx + __logf(pr) - zi;        // native v_log_f32

            part += __shfl_xor(part, 16);
            part += __shfl_xor(part, 32);

            if (lane < 16)
                out[(size_t)(rowBase + rw * 16 + lane) * 192 + colBlk] = part;
        }
    }
}

extern "C" void kernel_launch(void* const* d_in, const int* in_sizes, int n_in,
                              void* d_out, int out_size, void* d_ws, size_t ws_size,
                              hipStream_t stream) {
    const float* digits = (const float*)d_in[0];  // [8,512,10]
    const float* styles = (const float*)d_in[1];  // [8,512,50]
    const float* images = (const float*)d_in[2];  // [8,512,3,64,64]
    const float* Wh     = (const float*)d_in[3];  // [60,512]
    const float* bh     = (const float*)d_in[4];  // [512]
    const float* W1     = (const float*)d_in[5];  // [512,160]
    const float* b1     = (const float*)d_in[6];  // [160]
    const float* W2     = (const float*)d_in[7];  // [160,12288]
    const float* b2     = (const float*)d_in[8];  // [12288]
    float* out = (float*)d_out;                   // [4096,192]

    const int R = 4096;

    // workspace (~10.6 MB): h | t | w2f | tf   (all bf16)
    __hip_bfloat16* h   = (__hip_bfloat16*)d_ws;
    __hip_bfloat16* tt  = h + (size_t)R * 512;
    __hip_bfloat16* w2f = tt + (size_t)R * 160;
    __hip_bfloat16* tf  = w2f + (size_t)12288 * 160;

    dim3 gridP(192, 5);
    w2_pack_kernel<<<gridP, 256, 0, stream>>>(W2, w2f);

    dec_hidden_kernel<<<R / 8, 512, 0, stream>>>(digits, styles, Wh, bh, h);
    hidden1_kernel<<<R / 8, 192, 0, stream>>>(h, W1, b1, tt);
    t_pack_kernel<<<320, 256, 0, stream>>>(tt, tf);

    dim3 grid3(192, 8);
    out_loss_mfma_kernel<<<grid3, 256, 0, stream>>>(tf, w2f, b2, images, out);
}

// Round 14
// 91.458 us; speedup vs baseline: 1.1642x; 1.1642x over previous
//
#include <hip/hip_runtime.h>
#include <hip/hip_bf16.h>
#include <math.h>

// Decoder: h = relu(cat @ W_h + b_h); t = selu(h @ W1 + b1);
// x = sigmoid(t @ W2 + b2); loss = sum_w(softplus(z) - z*img)   [== -(BCE log-lik)]
// R = S*B = 4096 rows; Hn=512, bott=160, P=12288 = 192 groups * 64 (w).

#define SELU_SCALE 1.0507009873554804934193349852946f
#define SELU_ALPHA 1.6732632423543772848170429916717f

typedef __attribute__((ext_vector_type(8))) short bf16x8;   // 8 bf16 (4 VGPRs)
typedef __attribute__((ext_vector_type(4))) float f32x4;    // MFMA accumulator

static __device__ __forceinline__ short f2bf(float x) {
    __hip_bfloat16 h = __float2bfloat16(x);
    short s;
    __builtin_memcpy(&s, &h, 2);
    return s;
}

// ---------------- K0: pack W2 into MFMA-fragment-native order --------------
// w2f chunk = (col16*5 + kk): 64 lanes x 8 bf16 (1 KB contiguous).
__global__ __launch_bounds__(256) void w2_pack_kernel(
    const float* __restrict__ W2,       // [160,12288]
    __hip_bfloat16* __restrict__ w2f)   // [768*5 chunks][512 shorts]
{
    __shared__ float tile[32][64];      // [k within 32][col within 64]
    const int colBase = blockIdx.x * 64;   // 192
    const int kkBase  = blockIdx.y * 32;   // 5
    const int tid = threadIdx.x;

    for (int i = tid; i < 32 * 64; i += 256)
        tile[i >> 6][i & 63] = W2[(size_t)(kkBase + (i >> 6)) * 12288 + colBase + (i & 63)];
    __syncthreads();

    const int c16 = tid >> 6;        // 0..3 (col16 within this block)
    const int lane = tid & 63;
    const int lr = lane & 15, lh = lane >> 4;

    bf16x8 v;
#pragma unroll
    for (int j = 0; j < 8; ++j)
        v[j] = f2bf(tile[lh * 8 + j][c16 * 16 + lr]);

    const size_t chunk = (size_t)(blockIdx.x * 4 + c16) * 5 + blockIdx.y;
    *(bf16x8*)((short*)w2f + chunk * 512 + lane * 8) = v;
}

// ---------------- K1': FUSED h -> t -> tf (h,t never touch HBM) ------------
// Block = 16 rows (one r16 chunk group), 512 threads, grid 256.
// Phase A: stage cat[16][60] in LDS. Phase B: h[16][512] in LDS (each
// thread owns one h-column, 16 rows). Phase C: t[16][160] in LDS (320
// threads: 160 cols x 2 row-halves). Phase D: pack the 5 tf chunks for
// these 16 rows directly (320 threads = 5 chunks x 64 lanes, one
// contiguous bf16x8 store each).
__global__ __launch_bounds__(512) void dec_fused_kernel(
    const float* __restrict__ digits,   // [R,10]
    const float* __restrict__ styles,   // [R,50]
    const float* __restrict__ Wh,       // [60,512]
    const float* __restrict__ bh,       // [512]
    const float* __restrict__ W1,       // [512,160]
    const float* __restrict__ b1,       // [160]
    __hip_bfloat16* __restrict__ tf)    // [1280 chunks][512 shorts]
{
    __shared__ float cat_s[16][60];     // 3.75 KB
    __shared__ float h_s[16 * 512];     // 32 KB
    __shared__ float t_s[16][161];      // 10.1 KB (pad: conflict-free pack)

    const int tid = threadIdx.x;
    const int rowBase = blockIdx.x * 16;

    // ---- A: stage concat rows ----
    for (int i = tid; i < 16 * 60; i += 512) {
        const int r = i / 60, k = i % 60;
        const int row = rowBase + r;
        cat_s[r][k] = (k < 10) ? digits[row * 10 + k]
                               : styles[row * 50 + (k - 10)];
    }
    __syncthreads();

    // ---- B: h = relu(cat @ Wh + bh); thread = one column, 16 rows ----
    {
        float acc[16];
        const float bias = bh[tid];
#pragma unroll
        for (int r = 0; r < 16; ++r) acc[r] = bias;
        for (int k = 0; k < 60; ++k) {
            const float w = Wh[k * 512 + tid];
#pragma unroll
            for (int r = 0; r < 16; ++r) acc[r] = fmaf(cat_s[r][k], w, acc[r]);
        }
#pragma unroll
        for (int r = 0; r < 16; ++r)
            h_s[r * 512 + tid] = fmaxf(acc[r], 0.0f);
    }
    __syncthreads();

    // ---- C: t = selu(h @ W1 + b1); 320 threads = 160 cols x 2 row-halves --
    if (tid < 320) {
        const int rh = (tid >= 160) ? 1 : 0;
        const int col = tid - rh * 160;
        const int r0 = rh * 8;
        float acc[8];
        const float bias = b1[col];
#pragma unroll
        for (int r = 0; r < 8; ++r) acc[r] = bias;

        for (int k = 0; k < 512; k += 4) {
            const float w0 = W1[(size_t)(k + 0) * 160 + col];
            const float w1 = W1[(size_t)(k + 1) * 160 + col];
            const float w2 = W1[(size_t)(k + 2) * 160 + col];
            const float w3 = W1[(size_t)(k + 3) * 160 + col];
#pragma unroll
            for (int r = 0; r < 8; ++r) {
                const float4 hv = *(const float4*)&h_s[(r0 + r) * 512 + k];
                float a = acc[r];
                a = fmaf(hv.x, w0, a);
                a = fmaf(hv.y, w1, a);
                a = fmaf(hv.z, w2, a);
                a = fmaf(hv.w, w3, a);
                acc[r] = a;
            }
        }
#pragma unroll
        for (int r = 0; r < 8; ++r) {
            const float z = acc[r];
            const float s = (z > 0.0f) ? (SELU_SCALE * z)
                                       : (SELU_SCALE * SELU_ALPHA * expm1f(z));
            t_s[r0 + r][col] = s;
        }
    }
    __syncthreads();

    // ---- D: pack 5 chunks (kk=0..4), 64 lanes each ----
    if (tid < 320) {
        const int kk = tid >> 6;        // 0..4
        const int l = tid & 63;
        const int lr = l & 15, lh = l >> 4;
        bf16x8 v;
#pragma unroll
        for (int j = 0; j < 8; ++j)
            v[j] = f2bf(t_s[lr][kk * 32 + lh * 8 + j]);
        *(bf16x8*)((short*)tf + ((size_t)blockIdx.x * 5 + kk) * 512 + l * 8) = v;
    }
}

// ---------------- K3: MFMA GEMM + fused sigmoid-BCE loss (R10 structure) ---
// grid (192, 32) col-fast; block 256 = 4 waves x 32 rows; tile 128x64.
// Stateless, no __syncthreads, wave-private image slab via DMA.
// ONLY change vs R10: launch_bounds(256, 5) -> 5 blocks/CU (LDS 160 KB
// exact fit, VGPR ~64 <= 102) for +25% latency-hiding TLP.
__global__ __launch_bounds__(256, 5) void out_loss_mfma_kernel(
    const __hip_bfloat16* __restrict__ tf,   // fragment-packed t
    const __hip_bfloat16* __restrict__ w2f,  // fragment-packed W2
    const float* __restrict__ b2,            // [12288]
    const float* __restrict__ images,        // [4096,12288]
    float* __restrict__ out)                 // [4096,192]
{
    __shared__ float ims[4][2048];           // 32 KB: per-wave 32x64 images

    const int tid = threadIdx.x;
    const int lane = tid & 63;
    const int wv = tid >> 6;
    const int rowBase = blockIdx.y * 128 + wv * 32;
    const int colBase = blockIdx.x * 64;
    const int lr = lane & 15;
    const int lh = lane >> 4;

    const short* wfb = (const short*)w2f;
    const short* tfb = (const short*)tf;
    const char* imb = (const char*)images;

    // ---- images DMA: 8 instrs, 4 contiguous 256B rows each, pre-swizzled --
    {
        const int rsub = lane >> 4;
        const int m = lane & 15;
#pragma unroll
        for (int w = 0; w < 8; ++w) {
            const int r = w * 4 + rsub;
            const size_t gb = (size_t)(rowBase + r) * 49152 + (size_t)colBase * 4
                            + (size_t)((16 * m) ^ ((r & 15) << 4));
            __builtin_amdgcn_global_load_lds((const uint32_t*)(imb + gb),
                (uint32_t*)&ims[wv][w * 256], 16, 0, 0);
        }
    }

    const int c16base = blockIdx.x * 4;     // w2 col16 chunk base
    const int r16base = rowBase >> 4;       // t row16 chunk base

    // ---- GEMM: all fragment loads coalesced 1-segment ----
    f32x4 acc[4][2] = {};   // [cw][rw]
#pragma unroll
    for (int kk = 0; kk < 5; ++kk) {
        bf16x8 bT[2], aW[4];
#pragma unroll
        for (int r = 0; r < 2; ++r)
            bT[r] = *(const bf16x8*)(tfb
                + ((size_t)(r16base + r) * 5 + kk) * 512 + lane * 8);
#pragma unroll
        for (int c = 0; c < 4; ++c)
            aW[c] = *(const bf16x8*)(wfb
                + ((size_t)(c16base + c) * 5 + kk) * 512 + lane * 8);
#pragma unroll
        for (int c = 0; c < 4; ++c)
#pragma unroll
            for (int r = 0; r < 2; ++r)
                acc[c][r] = __builtin_amdgcn_mfma_f32_16x16x32_bf16(
                    aW[c], bT[r], acc[c][r], 0, 0, 0);
    }

    // bias quads (L2-hot); col = colBase + c*16 + lh*4 + j
    float4 bc[4];
#pragma unroll
    for (int c = 0; c < 4; ++c)
        bc[c] = *(const float4*)(b2 + colBase + c * 16 + lh * 4);

    // drain staging DMA + frag loads; per-wave private data -> no barrier
    asm volatile("s_waitcnt vmcnt(0)" ::: "memory");
    __builtin_amdgcn_sched_barrier(0);

    const float* myq = ims[wv];
#pragma unroll
    for (int rw = 0; rw < 2; ++rw) {
        float mx = 0.f;   // Σ max(z,0)
        float pr = 1.f;   // Π (1+e^{-|z|})  (16 terms, fp32-safe)
        float zi = 0.f;   // Σ z*im
#pragma unroll
        for (int c = 0; c < 4; ++c) {
            const int fidx = (rw * 16 + lr) * 64 + ((lh * 4 + c * 16) ^ (lr << 2));
            const float4 im4 = *(const float4*)&myq[fidx];   // ds_read_b128
            const float imv[4] = {im4.x, im4.y, im4.z, im4.w};
            const float bcv[4] = {bc[c].x, bc[c].y, bc[c].z, bc[c].w};
#pragma unroll
            for (int j = 0; j < 4; ++j) {
                const float z = acc[c][rw][j] + bcv[j];
                mx += fmaxf(z, 0.0f);
                pr *= 1.0f + __expf(-fabsf(z));   // native v_exp_f32
                zi = fmaf(z, imv[j], zi);
            }
        }
        float part = mx + __logf(pr) - zi;        // native v_log_f32

        // reduce over the 4 lh groups (each holds 16 of the 64 w-cols)
        part += __shfl_xor(part, 16);
        part += __shfl_xor(part, 32);

        if (lane < 16)
            out[(size_t)(rowBase + rw * 16 + lane) * 192 + blockIdx.x] = part;
    }
}

extern "C" void kernel_launch(void* const* d_in, const int* in_sizes, int n_in,
                              void* d_out, int out_size, void* d_ws, size_t ws_size,
                              hipStream_t stream) {
    const float* digits = (const float*)d_in[0];  // [8,512,10]
    const float* styles = (const float*)d_in[1];  // [8,512,50]
    const float* images = (const float*)d_in[2];  // [8,512,3,64,64]
    const float* Wh     = (const float*)d_in[3];  // [60,512]
    const float* bh     = (const float*)d_in[4];  // [512]
    const float* W1     = (const float*)d_in[5];  // [512,160]
    const float* b1     = (const float*)d_in[6];  // [160]
    const float* W2     = (const float*)d_in[7];  // [160,12288]
    const float* b2     = (const float*)d_in[8];  // [12288]
    float* out = (float*)d_out;                   // [4096,192]

    // workspace (~5.3 MB): w2f bf16 [3840*512] | tf bf16 [1280*512]
    __hip_bfloat16* w2f = (__hip_bfloat16*)d_ws;
    __hip_bfloat16* tf  = w2f + (size_t)12288 * 160;

    dim3 gridP(192, 5);
    w2_pack_kernel<<<gridP, 256, 0, stream>>>(W2, w2f);

    dec_fused_kernel<<<256, 512, 0, stream>>>(digits, styles, Wh, bh, W1, b1, tf);

    dim3 grid3(192, 32);
    out_loss_mfma_kernel<<<grid3, 256, 0, stream>>>(tf, w2f, b2, images, out);
}